// Round 1
// baseline (266.796 us; speedup 1.0000x reference)
//
#include <hip/hip_runtime.h>

#define BATCH 1024
#define SEQ   200
#define EMB   128

typedef __attribute__((ext_vector_type(8))) short short8;
typedef __attribute__((ext_vector_type(4))) float f32x4;

__device__ __forceinline__ unsigned short f2bf(float x) {
  unsigned u = __float_as_uint(x);
  u += 0x7fffu + ((u >> 16) & 1u);   // round-to-nearest-even
  return (unsigned short)(u >> 16);
}
__device__ __forceinline__ float bf2f(unsigned short b) {
  return __uint_as_float(((unsigned)b) << 16);
}

// ---------------------------------------------------------------------------
// Phase 1: ip[r][f] = sum_e emb[x[r]][e] * Win[f][e]   (bias added in phase 2)
// r = b*SEQ + s, 204800 rows. bf16 MFMA 16x16x32, output stored as bf16.
// Block: 256 threads = 4 waves, each wave one 16-row M-tile; 64 rows/block.
// ---------------------------------------------------------------------------
__global__ __launch_bounds__(256) void proj_mfma(
    const int* __restrict__ xidx, const float* __restrict__ emb,
    const float* __restrict__ Win, unsigned short* __restrict__ ip)
{
  const int tid = threadIdx.x;
  const int w   = tid >> 6;
  const int l   = tid & 63;
  const int l15 = l & 15;
  const int lhi = l >> 4;   // 0..3

  // B fragments: lane l, frag[nt][kc], elem j holds
  //   B[k = kc*32 + lhi*8 + j][n = nt*16 + l15] = Win[n][k]  (Win rows are K-contiguous)
  short8 bfrag[8][4];
#pragma unroll
  for (int nt = 0; nt < 8; ++nt) {
    const float* wp = Win + (nt*16 + l15)*EMB;
#pragma unroll
    for (int kc = 0; kc < 4; ++kc) {
      const float4* p = (const float4*)(wp + kc*32 + lhi*8);
      float4 a = p[0], b = p[1];
      short8 fr;
      fr[0]=(short)f2bf(a.x); fr[1]=(short)f2bf(a.y);
      fr[2]=(short)f2bf(a.z); fr[3]=(short)f2bf(a.w);
      fr[4]=(short)f2bf(b.x); fr[5]=(short)f2bf(b.y);
      fr[6]=(short)f2bf(b.z); fr[7]=(short)f2bf(b.w);
      bfrag[nt][kc] = fr;
    }
  }

  const int rb = blockIdx.x*64 + w*16;
  const int r  = rb + l15;
  const long xe = (long)xidx[r] * EMB;
  short8 afrag[4];
#pragma unroll
  for (int kc = 0; kc < 4; ++kc) {
    const float4* p = (const float4*)(emb + xe + kc*32 + lhi*8);
    float4 a = p[0], b = p[1];
    short8 fr;
    fr[0]=(short)f2bf(a.x); fr[1]=(short)f2bf(a.y);
    fr[2]=(short)f2bf(a.z); fr[3]=(short)f2bf(a.w);
    fr[4]=(short)f2bf(b.x); fr[5]=(short)f2bf(b.y);
    fr[6]=(short)f2bf(b.z); fr[7]=(short)f2bf(b.w);
    afrag[kc] = fr;
  }

  f32x4 acc[8];
#pragma unroll
  for (int nt = 0; nt < 8; ++nt) acc[nt] = (f32x4)(0.0f);
#pragma unroll
  for (int kc = 0; kc < 4; ++kc) {
#pragma unroll
    for (int nt = 0; nt < 8; ++nt)
      acc[nt] = __builtin_amdgcn_mfma_f32_16x16x32_bf16(afrag[kc], bfrag[nt][kc], acc[nt], 0, 0, 0);
  }

  // C/D layout (m89-verified): col = l&15, row = (l>>4)*4 + reg
#pragma unroll
  for (int nt = 0; nt < 8; ++nt) {
    const int fcol = nt*16 + l15;
#pragma unroll
    for (int j = 0; j < 4; ++j) {
      ip[(rb + lhi*4 + j)*EMB + fcol] = f2bf(acc[nt][j]);
    }
  }
}

// ---------------------------------------------------------------------------
// Phase 2: persistent recurrence. 256 blocks x 512 threads; block owns 4 rows.
// Thread t: f-pair f0=(t&63)*2, e-group eg=t>>6 (16 e's), W_h^T slice in regs.
// Partials reduced via LDS; finalize thread (row=t>>7, ff=t&127) does tanh.
// FUSED=1 recomputes the input projection in-kernel (no scratch needed).
// ---------------------------------------------------------------------------
template<int FUSED>
__global__ __launch_bounds__(512) void rnn_recur(
    const int* __restrict__ xidx, const float* __restrict__ emb,
    const float* __restrict__ Win, const float* __restrict__ bin,
    const float* __restrict__ Wh,  const float* __restrict__ bh,
    const unsigned short* __restrict__ ip, float* __restrict__ out)
{
  __shared__ float h_lds[4][EMB];
  __shared__ float part[8][4][EMB];
  __shared__ float emb_lds[FUSED ? 2 : 1][4][EMB];
  __shared__ int   x_lds[FUSED ? 4 : 1][SEQ];
  __shared__ float red[8];

  const int t   = threadIdx.x;
  const int f0  = (t & 63) * 2;
  const int eg  = t >> 6;          // 0..7
  const int e0  = eg * 16;
  const int b0  = blockIdx.x * 4;
  const int row = t >> 7;          // 0..3 (finalize role)
  const int ff  = t & 127;         // finalize f

  // W_h^T slice into registers: wh0[i] = Wh[f0  ][e0+i], wh1[i] = Wh[f0+1][e0+i]
  float wh0[16], wh1[16];
  float wi0[16], wi1[16];
  {
    const float* p0 = Wh + f0*EMB + e0;
    const float* p1 = Wh + (f0+1)*EMB + e0;
#pragma unroll
    for (int q = 0; q < 4; ++q) {
      float4 a = ((const float4*)p0)[q];
      wh0[4*q+0]=a.x; wh0[4*q+1]=a.y; wh0[4*q+2]=a.z; wh0[4*q+3]=a.w;
      float4 b = ((const float4*)p1)[q];
      wh1[4*q+0]=b.x; wh1[4*q+1]=b.y; wh1[4*q+2]=b.z; wh1[4*q+3]=b.w;
    }
  }
  if (FUSED) {
    const float* p0 = Win + f0*EMB + e0;
    const float* p1 = Win + (f0+1)*EMB + e0;
#pragma unroll
    for (int q = 0; q < 4; ++q) {
      float4 a = ((const float4*)p0)[q];
      wi0[4*q+0]=a.x; wi0[4*q+1]=a.y; wi0[4*q+2]=a.z; wi0[4*q+3]=a.w;
      float4 b = ((const float4*)p1)[q];
      wi1[4*q+0]=b.x; wi1[4*q+1]=b.y; wi1[4*q+2]=b.z; wi1[4*q+3]=b.w;
    }
  }

  const float bc = bin[ff] + bh[ff];

  h_lds[row][ff] = 0.0f;
  if (FUSED) {
    for (int i = t; i < 4*SEQ; i += 512)
      x_lds[i / SEQ][i % SEQ] = xidx[(b0 + i/SEQ)*SEQ + (i % SEQ)];
  }
  __syncthreads();

  float cur_ip = 0.0f;
  if (FUSED) {
    emb_lds[0][row][ff] = emb[(long)x_lds[row][0]*EMB + ff];
  } else {
    cur_ip = bf2f(ip[((b0+row)*SEQ + 0)*EMB + ff]);
  }
  __syncthreads();

  int cur = 0;
  for (int s = 0; s < SEQ; ++s) {
    // prefetch next step's ip / emb row (consumed after 2 barriers -> latency hidden)
    float nxt = 0.0f;
    if (s + 1 < SEQ) {
      if (FUSED) nxt = emb[(long)x_lds[row][s+1]*EMB + ff];
      else       nxt = bf2f(ip[((b0+row)*SEQ + s + 1)*EMB + ff]);
    }

    float pa0[4], pa1[4];
#pragma unroll
    for (int rr = 0; rr < 4; ++rr) { pa0[rr] = 0.0f; pa1[rr] = 0.0f; }
#pragma unroll
    for (int rr = 0; rr < 4; ++rr) {
      const float4* hp = (const float4*)&h_lds[rr][e0];   // broadcast reads
#pragma unroll
      for (int q = 0; q < 4; ++q) {
        float4 hv = hp[q];
        pa0[rr] = fmaf(hv.x, wh0[4*q+0], pa0[rr]);
        pa0[rr] = fmaf(hv.y, wh0[4*q+1], pa0[rr]);
        pa0[rr] = fmaf(hv.z, wh0[4*q+2], pa0[rr]);
        pa0[rr] = fmaf(hv.w, wh0[4*q+3], pa0[rr]);
        pa1[rr] = fmaf(hv.x, wh1[4*q+0], pa1[rr]);
        pa1[rr] = fmaf(hv.y, wh1[4*q+1], pa1[rr]);
        pa1[rr] = fmaf(hv.z, wh1[4*q+2], pa1[rr]);
        pa1[rr] = fmaf(hv.w, wh1[4*q+3], pa1[rr]);
      }
      if (FUSED) {
        const float4* epv = (const float4*)&emb_lds[cur][rr][e0];
#pragma unroll
        for (int q = 0; q < 4; ++q) {
          float4 ev = epv[q];
          pa0[rr] = fmaf(ev.x, wi0[4*q+0], pa0[rr]);
          pa0[rr] = fmaf(ev.y, wi0[4*q+1], pa0[rr]);
          pa0[rr] = fmaf(ev.z, wi0[4*q+2], pa0[rr]);
          pa0[rr] = fmaf(ev.w, wi0[4*q+3], pa0[rr]);
          pa1[rr] = fmaf(ev.x, wi1[4*q+0], pa1[rr]);
          pa1[rr] = fmaf(ev.y, wi1[4*q+1], pa1[rr]);
          pa1[rr] = fmaf(ev.z, wi1[4*q+2], pa1[rr]);
          pa1[rr] = fmaf(ev.w, wi1[4*q+3], pa1[rr]);
        }
      }
    }
#pragma unroll
    for (int rr = 0; rr < 4; ++rr) {
      part[eg][rr][f0]   = pa0[rr];
      part[eg][rr][f0+1] = pa1[rr];
    }
    __syncthreads();

    // finalize: each thread owns one (row, ff) output
    float acc = bc + (FUSED ? 0.0f : cur_ip);
#pragma unroll
    for (int g = 0; g < 8; ++g) acc += part[g][row][ff];
    float hn = tanhf(acc);
    if (FUSED && (s + 1 < SEQ)) emb_lds[cur ^ 1][row][ff] = nxt;
    h_lds[row][ff] = hn;
    __syncthreads();

    if (!FUSED) cur_ip = nxt;
    cur ^= 1;
  }

  // epilogue: L2 normalize each row (row spans waves 2*row, 2*row+1)
  float hv = h_lds[row][ff];
  float sq = hv * hv;
#pragma unroll
  for (int off = 32; off > 0; off >>= 1) sq += __shfl_xor(sq, off, 64);
  if ((t & 63) == 0) red[t >> 6] = sq;
  __syncthreads();
  float nrm = sqrtf(red[row*2] + red[row*2 + 1]);
  out[(b0 + row)*EMB + ff] = hv / fmaxf(nrm, 1e-12f);
}

// ---------------------------------------------------------------------------
extern "C" void kernel_launch(void* const* d_in, const int* in_sizes, int n_in,
                              void* d_out, int out_size, void* d_ws, size_t ws_size,
                              hipStream_t stream) {
  const int*   x    = (const int*)  d_in[0];
  const float* emb  = (const float*)d_in[1];
  const float* Win  = (const float*)d_in[2];
  const float* bin  = (const float*)d_in[3];
  const float* Wh   = (const float*)d_in[4];
  const float* bh   = (const float*)d_in[5];
  float* out = (float*)d_out;

  const size_t need = (size_t)BATCH * SEQ * EMB * sizeof(unsigned short); // 52.4 MB
  if (ws_size >= need) {
    unsigned short* ip = (unsigned short*)d_ws;
    proj_mfma<<<(BATCH*SEQ)/64, 256, 0, stream>>>(x, emb, Win, ip);
    rnn_recur<0><<<BATCH/4, 512, 0, stream>>>(x, emb, Win, bin, Wh, bh, ip, out);
  } else {
    rnn_recur<1><<<BATCH/4, 512, 0, stream>>>(x, emb, Win, bin, Wh, bh, nullptr, out);
  }
}

// Round 2
// 263.821 us; speedup vs baseline: 1.0113x; 1.0113x over previous
//
#include <hip/hip_runtime.h>

#define BATCH 1024
#define SEQ   200
#define EMB   128

typedef __attribute__((ext_vector_type(8))) short short8;
typedef __attribute__((ext_vector_type(4))) float f32x4;

__device__ __forceinline__ unsigned short f2bf(float x) {
  unsigned u = __float_as_uint(x);
  u += 0x7fffu + ((u >> 16) & 1u);   // round-to-nearest-even
  return (unsigned short)(u >> 16);
}
__device__ __forceinline__ float bf2f(unsigned short b) {
  return __uint_as_float(((unsigned)b) << 16);
}

// ---------------------------------------------------------------------------
// cvt: Win (fp32) -> bf16, once. 16384 elements.
// ---------------------------------------------------------------------------
__global__ void cvt_bf16(const float* __restrict__ src,
                         unsigned short* __restrict__ dst, int n) {
  int i = blockIdx.x * 256 + threadIdx.x;
  if (i < n) dst[i] = f2bf(src[i]);
}

// ---------------------------------------------------------------------------
// Phase 1: ip[r][f] = sum_e emb[x[r]][e] * Win[f][e]  (bias added in phase 2)
// B sourced from pre-converted bf16 (no per-thread convert), 2 M-tiles/wave.
// 1600 blocks x 256 thr; block covers 128 rows.
// ---------------------------------------------------------------------------
__global__ __launch_bounds__(256) void proj2(
    const int* __restrict__ xidx, const float* __restrict__ emb,
    const unsigned short* __restrict__ Wb, unsigned short* __restrict__ ip)
{
  const int tid = threadIdx.x;
  const int w   = tid >> 6;
  const int l   = tid & 63;
  const int l15 = l & 15;
  const int lhi = l >> 4;

  // B fragments: lane l, elem j holds B[k=kc*32+lhi*8+j][n=nt*16+l15] = Win[n][k]
  short8 bfrag[8][4];
#pragma unroll
  for (int nt = 0; nt < 8; ++nt)
#pragma unroll
    for (int kc = 0; kc < 4; ++kc)
      bfrag[nt][kc] = *(const short8*)(Wb + (nt*16 + l15)*EMB + kc*32 + lhi*8);

#pragma unroll
  for (int t = 0; t < 2; ++t) {
    const int m  = blockIdx.x*8 + w*2 + t;
    const int rb = m * 16;
    const long xe = (long)xidx[rb + l15] * EMB;
    short8 afrag[4];
#pragma unroll
    for (int kc = 0; kc < 4; ++kc) {
      const float4* p = (const float4*)(emb + xe + kc*32 + lhi*8);
      float4 a = p[0], b = p[1];
      short8 fr;
      fr[0]=(short)f2bf(a.x); fr[1]=(short)f2bf(a.y);
      fr[2]=(short)f2bf(a.z); fr[3]=(short)f2bf(a.w);
      fr[4]=(short)f2bf(b.x); fr[5]=(short)f2bf(b.y);
      fr[6]=(short)f2bf(b.z); fr[7]=(short)f2bf(b.w);
      afrag[kc] = fr;
    }
    f32x4 acc[8];
#pragma unroll
    for (int nt = 0; nt < 8; ++nt) acc[nt] = (f32x4)(0.0f);
#pragma unroll
    for (int kc = 0; kc < 4; ++kc)
#pragma unroll
      for (int nt = 0; nt < 8; ++nt)
        acc[nt] = __builtin_amdgcn_mfma_f32_16x16x32_bf16(afrag[kc], bfrag[nt][kc], acc[nt], 0, 0, 0);
    // D layout: col = l&15, row = (l>>4)*4 + j (m89-verified, passed round 1)
#pragma unroll
    for (int nt = 0; nt < 8; ++nt)
#pragma unroll
      for (int j = 0; j < 4; ++j)
        ip[(long)(rb + lhi*4 + j)*EMB + nt*16 + l15] = f2bf(acc[nt][j]);
  }
}

// ---------------------------------------------------------------------------
// Phase 2: MFMA recurrence. 64 blocks x 256 thr (4 waves); block owns 16 rows.
// Per step: h_tile[16x128] (bf16 hi+lo, XOR-swizzled, double-buffered LDS)
//   -> A-frags; Wh hi+lo resident as B-frags; 3-term split-bf16 MFMA
//   (AhiBhi + AloBhi + AhiBlo) keeps recurrence fp32-faithful (~1e-5).
// One barrier per step. Wave w computes N-tiles nt = 2w, 2w+1.
// ---------------------------------------------------------------------------
__global__ __launch_bounds__(256) void rnn_mfma(
    const unsigned short* __restrict__ ip, const float* __restrict__ Wh,
    const float* __restrict__ bin, const float* __restrict__ bh,
    float* __restrict__ out)
{
  __shared__ unsigned short hbuf[2][2][2048];  // [buf][hi/lo][16 rows x 128 e]
  __shared__ float red[16][4];
  __shared__ float ninv[16];

  const int tid = threadIdx.x;
  const int w   = tid >> 6;
  const int l   = tid & 63;
  const int l15 = l & 15;
  const int lhi = l >> 4;

  // B fragments of Wh, split hi/lo:  B[k][n] = Wh[n][k], n = nt*16+l15
  short8 bhi[2][4], blo[2][4];
  float bias[2];
#pragma unroll
  for (int nt2 = 0; nt2 < 2; ++nt2) {
    const int f = (2*w + nt2)*16 + l15;
    bias[nt2] = bin[f] + bh[f];
    const float* wr = Wh + f*EMB;
#pragma unroll
    for (int kc = 0; kc < 4; ++kc) {
      const float4* p = (const float4*)(wr + kc*32 + lhi*8);
      float4 a = p[0], b = p[1];
      float v[8] = {a.x, a.y, a.z, a.w, b.x, b.y, b.z, b.w};
      short8 h8, l8;
#pragma unroll
      for (int j = 0; j < 8; ++j) {
        unsigned short hq = f2bf(v[j]);
        h8[j] = (short)hq;
        l8[j] = (short)f2bf(v[j] - bf2f(hq));
      }
      bhi[nt2][kc] = h8;
      blo[nt2][kc] = l8;
    }
  }

  // zero h (buffer 0, hi+lo tiles): h0 = 0
  {
    unsigned int* z = (unsigned int*)&hbuf[0][0][0];
    for (int i = tid; i < 2048; i += 256) z[i] = 0u;
  }

  // ip base pointers per (nt2, j): batch row rb = blk*16 + lhi*4 + j, col f
  const unsigned short* ipp[2][4];
#pragma unroll
  for (int nt2 = 0; nt2 < 2; ++nt2)
#pragma unroll
    for (int j = 0; j < 4; ++j)
      ipp[nt2][j] = ip + ((size_t)(blockIdx.x*16 + lhi*4 + j) * SEQ) * EMB
                       + (2*w + nt2)*16 + l15;

  unsigned short pre[2][4];
#pragma unroll
  for (int nt2 = 0; nt2 < 2; ++nt2)
#pragma unroll
    for (int j = 0; j < 4; ++j) pre[nt2][j] = ipp[nt2][j][0];

  __syncthreads();

  float hfin[2][4];
  for (int s = 0; s < SEQ; ++s) {
    const char* thi = (const char*)&hbuf[s & 1][0][0];
    const char* tlo = (const char*)&hbuf[s & 1][1][0];
    // A-frags: lane holds A[row=l15][k=kc*32+lhi*8 .. +7]; swizzle ^(row&7)<<4
    short8 ahi[4], alo[4];
#pragma unroll
    for (int kc = 0; kc < 4; ++kc) {
      int byte = l15*256 + kc*64 + lhi*16;
      byte ^= ((l15 & 7) << 4);
      ahi[kc] = *(const short8*)(thi + byte);
      alo[kc] = *(const short8*)(tlo + byte);
    }
    char* nhi = (char*)&hbuf[(s & 1) ^ 1][0][0];
    char* nlo = (char*)&hbuf[(s & 1) ^ 1][1][0];
#pragma unroll
    for (int nt2 = 0; nt2 < 2; ++nt2) {
      f32x4 a0 = (f32x4)(0.0f), a1 = (f32x4)(0.0f), a2 = (f32x4)(0.0f);
#pragma unroll
      for (int kc = 0; kc < 4; ++kc) {
        a0 = __builtin_amdgcn_mfma_f32_16x16x32_bf16(ahi[kc], bhi[nt2][kc], a0, 0, 0, 0);
        a1 = __builtin_amdgcn_mfma_f32_16x16x32_bf16(alo[kc], bhi[nt2][kc], a1, 0, 0, 0);
        a2 = __builtin_amdgcn_mfma_f32_16x16x32_bf16(ahi[kc], blo[nt2][kc], a2, 0, 0, 0);
      }
#pragma unroll
      for (int j = 0; j < 4; ++j) {
        float v  = a0[j] + a1[j] + a2[j] + bias[nt2] + bf2f(pre[nt2][j]);
        float e2 = __expf(2.0f * v);
        float hn = 1.0f - __fdividef(2.0f, e2 + 1.0f);
        hfin[nt2][j] = hn;
        const int row = lhi*4 + j;
        int byte = row*256 + ((2*w + nt2)*16 + l15)*2;
        byte ^= ((row & 7) << 4);
        unsigned short hq = f2bf(hn);
        *(unsigned short*)(nhi + byte) = hq;
        *(unsigned short*)(nlo + byte) = f2bf(hn - bf2f(hq));
      }
    }
    const int sn = (s + 1 < SEQ) ? s + 1 : s;
#pragma unroll
    for (int nt2 = 0; nt2 < 2; ++nt2)
#pragma unroll
      for (int j = 0; j < 4; ++j) pre[nt2][j] = ipp[nt2][j][(size_t)sn * EMB];
    __syncthreads();
  }

  // L2 normalize: per row r = lhi*4+j, sum over 128 cols.
  float pj[4];
#pragma unroll
  for (int j = 0; j < 4; ++j)
    pj[j] = hfin[0][j]*hfin[0][j] + hfin[1][j]*hfin[1][j];
#pragma unroll
  for (int off = 1; off < 16; off <<= 1)
#pragma unroll
    for (int j = 0; j < 4; ++j) pj[j] += __shfl_xor(pj[j], off, 64);
  if (l15 == 0) {
#pragma unroll
    for (int j = 0; j < 4; ++j) red[lhi*4 + j][w] = pj[j];
  }
  __syncthreads();
  if (tid < 16) {
    float nv = red[tid][0] + red[tid][1] + red[tid][2] + red[tid][3];
    ninv[tid] = 1.0f / fmaxf(sqrtf(nv), 1e-12f);
  }
  __syncthreads();
#pragma unroll
  for (int nt2 = 0; nt2 < 2; ++nt2)
#pragma unroll
    for (int j = 0; j < 4; ++j) {
      const int row = lhi*4 + j;
      out[((size_t)(blockIdx.x*16 + row))*EMB + (2*w + nt2)*16 + l15] =
          hfin[nt2][j] * ninv[row];
    }
}

// ---------------------------------------------------------------------------
// Fallback (small ws): fused VALU recurrence from round 1 (known-correct).
// ---------------------------------------------------------------------------
__global__ __launch_bounds__(512) void rnn_fused(
    const int* __restrict__ xidx, const float* __restrict__ emb,
    const float* __restrict__ Win, const float* __restrict__ bin,
    const float* __restrict__ Wh,  const float* __restrict__ bh,
    float* __restrict__ out)
{
  __shared__ float h_lds[4][EMB];
  __shared__ float part[8][4][EMB];
  __shared__ float emb_lds[2][4][EMB];
  __shared__ int   x_lds[4][SEQ];
  __shared__ float red[8];

  const int t   = threadIdx.x;
  const int f0  = (t & 63) * 2;
  const int eg  = t >> 6;
  const int e0  = eg * 16;
  const int b0  = blockIdx.x * 4;
  const int row = t >> 7;
  const int ff  = t & 127;

  float wh0[16], wh1[16], wi0[16], wi1[16];
  {
    const float* p0 = Wh + f0*EMB + e0;
    const float* p1 = Wh + (f0+1)*EMB + e0;
    const float* q0 = Win + f0*EMB + e0;
    const float* q1 = Win + (f0+1)*EMB + e0;
#pragma unroll
    for (int q = 0; q < 4; ++q) {
      float4 a = ((const float4*)p0)[q];
      wh0[4*q+0]=a.x; wh0[4*q+1]=a.y; wh0[4*q+2]=a.z; wh0[4*q+3]=a.w;
      float4 b = ((const float4*)p1)[q];
      wh1[4*q+0]=b.x; wh1[4*q+1]=b.y; wh1[4*q+2]=b.z; wh1[4*q+3]=b.w;
      float4 c = ((const float4*)q0)[q];
      wi0[4*q+0]=c.x; wi0[4*q+1]=c.y; wi0[4*q+2]=c.z; wi0[4*q+3]=c.w;
      float4 d = ((const float4*)q1)[q];
      wi1[4*q+0]=d.x; wi1[4*q+1]=d.y; wi1[4*q+2]=d.z; wi1[4*q+3]=d.w;
    }
  }
  const float bc = bin[ff] + bh[ff];
  h_lds[row][ff] = 0.0f;
  for (int i = t; i < 4*SEQ; i += 512)
    x_lds[i / SEQ][i % SEQ] = xidx[(b0 + i/SEQ)*SEQ + (i % SEQ)];
  __syncthreads();
  emb_lds[0][row][ff] = emb[(long)x_lds[row][0]*EMB + ff];
  __syncthreads();

  int cur = 0;
  for (int s = 0; s < SEQ; ++s) {
    float nxt = 0.0f;
    if (s + 1 < SEQ) nxt = emb[(long)x_lds[row][s+1]*EMB + ff];
    float pa0[4], pa1[4];
#pragma unroll
    for (int rr = 0; rr < 4; ++rr) { pa0[rr] = 0.0f; pa1[rr] = 0.0f; }
#pragma unroll
    for (int rr = 0; rr < 4; ++rr) {
      const float4* hp  = (const float4*)&h_lds[rr][e0];
      const float4* epv = (const float4*)&emb_lds[cur][rr][e0];
#pragma unroll
      for (int q = 0; q < 4; ++q) {
        float4 hv = hp[q], ev = epv[q];
        pa0[rr] = fmaf(hv.x, wh0[4*q+0], pa0[rr]); pa0[rr] = fmaf(hv.y, wh0[4*q+1], pa0[rr]);
        pa0[rr] = fmaf(hv.z, wh0[4*q+2], pa0[rr]); pa0[rr] = fmaf(hv.w, wh0[4*q+3], pa0[rr]);
        pa1[rr] = fmaf(hv.x, wh1[4*q+0], pa1[rr]); pa1[rr] = fmaf(hv.y, wh1[4*q+1], pa1[rr]);
        pa1[rr] = fmaf(hv.z, wh1[4*q+2], pa1[rr]); pa1[rr] = fmaf(hv.w, wh1[4*q+3], pa1[rr]);
        pa0[rr] = fmaf(ev.x, wi0[4*q+0], pa0[rr]); pa0[rr] = fmaf(ev.y, wi0[4*q+1], pa0[rr]);
        pa0[rr] = fmaf(ev.z, wi0[4*q+2], pa0[rr]); pa0[rr] = fmaf(ev.w, wi0[4*q+3], pa0[rr]);
        pa1[rr] = fmaf(ev.x, wi1[4*q+0], pa1[rr]); pa1[rr] = fmaf(ev.y, wi1[4*q+1], pa1[rr]);
        pa1[rr] = fmaf(ev.z, wi1[4*q+2], pa1[rr]); pa1[rr] = fmaf(ev.w, wi1[4*q+3], pa1[rr]);
      }
    }
#pragma unroll
    for (int rr = 0; rr < 4; ++rr) {
      part[eg][rr][f0]   = pa0[rr];
      part[eg][rr][f0+1] = pa1[rr];
    }
    __syncthreads();
    float acc = bc;
#pragma unroll
    for (int g = 0; g < 8; ++g) acc += part[g][row][ff];
    float hn = tanhf(acc);
    if (s + 1 < SEQ) emb_lds[cur ^ 1][row][ff] = nxt;
    h_lds[row][ff] = hn;
    __syncthreads();
    cur ^= 1;
  }
  float hv = h_lds[row][ff];
  float sq = hv * hv;
#pragma unroll
  for (int off = 32; off > 0; off >>= 1) sq += __shfl_xor(sq, off, 64);
  if ((t & 63) == 0) red[t >> 6] = sq;
  __syncthreads();
  float nrm = sqrtf(red[row*2] + red[row*2 + 1]);
  out[(b0 + row)*EMB + ff] = hv / fmaxf(nrm, 1e-12f);
}

// ---------------------------------------------------------------------------
extern "C" void kernel_launch(void* const* d_in, const int* in_sizes, int n_in,
                              void* d_out, int out_size, void* d_ws, size_t ws_size,
                              hipStream_t stream) {
  const int*   x    = (const int*)  d_in[0];
  const float* emb  = (const float*)d_in[1];
  const float* Win  = (const float*)d_in[2];
  const float* bin  = (const float*)d_in[3];
  const float* Wh   = (const float*)d_in[4];
  const float* bh   = (const float*)d_in[5];
  float* out = (float*)d_out;

  const size_t ip_bytes = (size_t)BATCH * SEQ * EMB * sizeof(unsigned short); // 52.4 MB
  const size_t need     = ip_bytes + EMB*EMB*sizeof(unsigned short);
  if (ws_size >= need) {
    unsigned short* ip = (unsigned short*)d_ws;
    unsigned short* Wb = (unsigned short*)((char*)d_ws + ip_bytes);
    cvt_bf16<<<(EMB*EMB + 255)/256, 256, 0, stream>>>(Win, Wb, EMB*EMB);
    proj2<<<(BATCH*SEQ)/128, 256, 0, stream>>>(x, emb, Wb, ip);
    rnn_mfma<<<BATCH/16, 256, 0, stream>>>(ip, Wh, bin, bh, out);
  } else {
    rnn_fused<<<BATCH/4, 512, 0, stream>>>(x, emb, Win, bin, Wh, bh, out);
  }
}

// Round 3
// 257.251 us; speedup vs baseline: 1.0371x; 1.0255x over previous
//
#include <hip/hip_runtime.h>

#define BATCH 1024
#define SEQ   200
#define EMB   128
#define VOCAB 100000

typedef __attribute__((ext_vector_type(8))) short short8;
typedef __attribute__((ext_vector_type(4))) float f32x4;

__device__ __forceinline__ unsigned short f2bf(float x) {
  unsigned u = __float_as_uint(x);
  u += 0x7fffu + ((u >> 16) & 1u);   // round-to-nearest-even
  return (unsigned short)(u >> 16);
}
__device__ __forceinline__ float bf2f(unsigned short b) {
  return __uint_as_float(((unsigned)b) << 16);
}

// async global->LDS, 16B per lane. LDS dest = wave-uniform base + lane*16.
__device__ __forceinline__ void async_ld16(const void* g, void* l) {
  __builtin_amdgcn_global_load_lds(
      (__attribute__((address_space(1))) unsigned int*)(void*)g,
      (__attribute__((address_space(3))) unsigned int*)l, 16, 0, 0);
}

// ---------------------------------------------------------------------------
// One-time: emb table fp32 -> bf16. 12.8M elems, 8/thread. ~77MB traffic.
// ---------------------------------------------------------------------------
__global__ __launch_bounds__(256) void cvt_emb(const float* __restrict__ src,
                                               unsigned short* __restrict__ dst) {
  size_t i = ((size_t)blockIdx.x * 256 + threadIdx.x) * 8;
  float4 a = *(const float4*)(src + i);
  float4 b = *(const float4*)(src + i + 4);
  short8 o;
  o[0]=(short)f2bf(a.x); o[1]=(short)f2bf(a.y); o[2]=(short)f2bf(a.z); o[3]=(short)f2bf(a.w);
  o[4]=(short)f2bf(b.x); o[5]=(short)f2bf(b.y); o[6]=(short)f2bf(b.z); o[7]=(short)f2bf(b.w);
  *(short8*)(dst + i) = o;
}

// ---------------------------------------------------------------------------
// Fused RNN: 64 blocks x 256 thr (4 waves); block owns 16 batch rows.
// Per step s (one raw barrier, counted vmcnt — loads stay in flight):
//   D'[f][r] = Win·emb_s + Wh_hi·h_hi + Wh_hi·h_lo + Wh_lo·h_hi  (swapped MFMA)
//   h_{s+1} = tanh(D' + bias), stored hi+lo bf16 to swizzled double-buffered LDS.
// emb rows gathered 7 steps ahead into an 8-slot LDS ring via global_load_lds
// (gather source pre-swizzled within the 256B row -> swizzled ring, rule 21).
// End of step: vmcnt(6) (slot s+1 complete in ALL waves) + lgkmcnt(0) + s_barrier.
// ---------------------------------------------------------------------------
__global__ __launch_bounds__(256, 1) void rnn3(
    const int* __restrict__ xidx, const unsigned short* __restrict__ embb,
    const float* __restrict__ Win, const float* __restrict__ bin,
    const float* __restrict__ Wh,  const float* __restrict__ bh,
    float* __restrict__ out)
{
  __shared__ unsigned short ring[8][2048];     // 8 slots x [16 r][128 f] bf16, swizzled
  __shared__ unsigned short hbuf[2][2][2048];  // [buf][hi|lo][16 r][128 f], swizzled
  __shared__ int   xl[16][SEQ];                // this block's indices
  __shared__ float red[16][4];

  const int tid = threadIdx.x;
  const int w   = tid >> 6;
  const int l   = tid & 63;
  const int l15 = l & 15;
  const int lhi = l >> 4;            // 0..3
  const int r0  = blockIdx.x * 16;   // batch rows r0..r0+15

  char* ring_c = (char*)&ring[0][0];
  char* hb_c   = (char*)&hbuf[0][0][0];

  // A-fragments (row = l15): wave w owns f-tiles nt = 2w, 2w+1.
  //   wi  = bf16(Win[f][k]);  whh/whl = hi/lo split of Wh[f][k]
  short8 wi[2][4], whh[2][4], whl[2][4];
  float bias[2][4];                  // [nt2][j] for OUTPUT f = nt*16 + lhi*4 + j
#pragma unroll
  for (int nt2 = 0; nt2 < 2; ++nt2) {
    const int frow = (2*w + nt2)*16 + l15;
    const float* pw = Win + frow*EMB;
    const float* ph = Wh  + frow*EMB;
#pragma unroll
    for (int kc = 0; kc < 4; ++kc) {
      float4 a = ((const float4*)(pw + kc*32 + lhi*8))[0];
      float4 b = ((const float4*)(pw + kc*32 + lhi*8))[1];
      float vw[8] = {a.x,a.y,a.z,a.w,b.x,b.y,b.z,b.w};
      float4 c = ((const float4*)(ph + kc*32 + lhi*8))[0];
      float4 d = ((const float4*)(ph + kc*32 + lhi*8))[1];
      float vh[8] = {c.x,c.y,c.z,c.w,d.x,d.y,d.z,d.w};
      short8 fw, fh, fl;
#pragma unroll
      for (int j = 0; j < 8; ++j) {
        fw[j] = (short)f2bf(vw[j]);
        unsigned short hq = f2bf(vh[j]);
        fh[j] = (short)hq;
        fl[j] = (short)f2bf(vh[j] - bf2f(hq));
      }
      wi[nt2][kc] = fw; whh[nt2][kc] = fh; whl[nt2][kc] = fl;
    }
    const int fo = (2*w + nt2)*16 + lhi*4;
#pragma unroll
    for (int j = 0; j < 4; ++j) bias[nt2][j] = bin[fo + j] + bh[fo + j];
  }

  // zero h buffer 0 (hi+lo = 8KB) ; stage x indices (12.8KB)
  for (int i = tid; i < 2048; i += 256) ((unsigned int*)hb_c)[i] = 0u;
  for (int i = tid; i < 16*SEQ; i += 256)
    xl[i / SEQ][i % SEQ] = xidx[(r0 + i/SEQ)*SEQ + (i % SEQ)];
  __syncthreads();  // full drain OK here (prologue, once)

  // gather geometry: lane loads 16B of ring row rr, column-chunk cb,
  // source pre-swizzled within the 256B emb row (involution key = rr&7)
  const int rr  = w*4 + (l >> 4);          // 0..15
  const int cb  = (l & 15) * 16;
  const int srcoff = cb ^ ((rr & 7) << 4);
  const char* ebase = (const char*)embb;

#pragma unroll
  for (int p = 0; p < 7; ++p)
    async_ld16(ebase + (size_t)xl[rr][p]*256 + srcoff,
               ring_c + p*4096 + w*1024);
  asm volatile("s_waitcnt vmcnt(6) lgkmcnt(0)\n\ts_barrier" ::: "memory");

  float hfin[2][4];
  for (int s = 0; s < SEQ; ++s) {
    // issue prefetch for step s+7 (clamped; keeps vmcnt invariant exact)
    {
      int t = s + 7; if (t >= SEQ) t = SEQ - 1;
      async_ld16(ebase + (size_t)xl[rr][t]*256 + srcoff,
                 ring_c + ((s+7)&7)*4096 + w*1024);
    }

    // B-fragments: lane holds B[k=kc*32+lhi*8+j][col=l15] from swizzled tiles
    const char* eb = ring_c + (s & 7)*4096;
    const char* th = hb_c   + (s & 1)*8192;
    short8 ef[4], hh[4], hl[4];
#pragma unroll
    for (int kc = 0; kc < 4; ++kc) {
      const int off = (l15*256 + kc*64 + lhi*16) ^ ((l15 & 7) << 4);
      ef[kc] = *(const short8*)(eb + off);
      hh[kc] = *(const short8*)(th + off);
      hl[kc] = *(const short8*)(th + 4096 + off);
    }

    char* nh = hb_c + (((s & 1) ^ 1))*8192;
#pragma unroll
    for (int nt2 = 0; nt2 < 2; ++nt2) {
      f32x4 a0 = (f32x4)(0.0f), a1 = (f32x4)(0.0f), a2 = (f32x4)(0.0f);
#pragma unroll
      for (int kc = 0; kc < 4; ++kc) {
        a0 = __builtin_amdgcn_mfma_f32_16x16x32_bf16(wi[nt2][kc],  ef[kc], a0, 0, 0, 0);
        a1 = __builtin_amdgcn_mfma_f32_16x16x32_bf16(whh[nt2][kc], hl[kc], a1, 0, 0, 0);
        a2 = __builtin_amdgcn_mfma_f32_16x16x32_bf16(whl[nt2][kc], hh[kc], a2, 0, 0, 0);
      }
#pragma unroll
      for (int kc = 0; kc < 4; ++kc)
        a0 = __builtin_amdgcn_mfma_f32_16x16x32_bf16(whh[nt2][kc], hh[kc], a0, 0, 0, 0);

      // D' layout: col=l15 -> batch row r, row=lhi*4+j -> f. Pack hi/lo, b64 write.
      unsigned long long hi4 = 0ull, lo4 = 0ull;
#pragma unroll
      for (int j = 0; j < 4; ++j) {
        float v  = a0[j] + a1[j] + a2[j] + bias[nt2][j];
        float e2 = __expf(2.0f * v);
        float hn = 1.0f - __fdividef(2.0f, e2 + 1.0f);
        hfin[nt2][j] = hn;
        unsigned short hq = f2bf(hn);
        unsigned short lq = f2bf(hn - bf2f(hq));
        hi4 |= (unsigned long long)hq << (16*j);
        lo4 |= (unsigned long long)lq << (16*j);
      }
      const int wo = (l15*256 + ((2*w + nt2)*16 + lhi*4)*2) ^ ((l15 & 7) << 4);
      *(unsigned long long*)(nh + wo)        = hi4;
      *(unsigned long long*)(nh + 4096 + wo) = lo4;
    }

    // slot s+1 complete in ALL waves before anyone enters step s+1;
    // h writes visible; loads for s+2..s+7 stay in flight (never vmcnt(0)).
    asm volatile("s_waitcnt vmcnt(6) lgkmcnt(0)\n\ts_barrier" ::: "memory");
  }

  // L2 normalize rows. Thread's 8 values all belong to row r = l15.
  float pj = 0.0f;
#pragma unroll
  for (int nt2 = 0; nt2 < 2; ++nt2)
#pragma unroll
    for (int j = 0; j < 4; ++j) pj += hfin[nt2][j]*hfin[nt2][j];
  pj += __shfl_xor(pj, 16, 64);
  pj += __shfl_xor(pj, 32, 64);
  if (lhi == 0) red[l15][w] = pj;
  asm volatile("s_waitcnt lgkmcnt(0)\n\ts_barrier" ::: "memory");
  const float tot = red[l15][0] + red[l15][1] + red[l15][2] + red[l15][3];
  const float inv = 1.0f / fmaxf(sqrtf(tot), 1e-12f);
#pragma unroll
  for (int nt2 = 0; nt2 < 2; ++nt2) {
    float4 o;
    o.x = hfin[nt2][0]*inv; o.y = hfin[nt2][1]*inv;
    o.z = hfin[nt2][2]*inv; o.w = hfin[nt2][3]*inv;
    *(float4*)(out + (size_t)(r0 + l15)*EMB + (2*w + nt2)*16 + lhi*4) = o;
  }
}

// ---------------------------------------------------------------------------
// Fallback (small ws): round-1 VALU recurrence (known-correct, no scratch).
// ---------------------------------------------------------------------------
__global__ __launch_bounds__(512) void rnn_fused(
    const int* __restrict__ xidx, const float* __restrict__ emb,
    const float* __restrict__ Win, const float* __restrict__ bin,
    const float* __restrict__ Wh,  const float* __restrict__ bh,
    float* __restrict__ out)
{
  __shared__ float h_lds[4][EMB];
  __shared__ float part[8][4][EMB];
  __shared__ float emb_lds[2][4][EMB];
  __shared__ int   x_lds[4][SEQ];
  __shared__ float red[8];

  const int t   = threadIdx.x;
  const int f0  = (t & 63) * 2;
  const int eg  = t >> 6;
  const int e0  = eg * 16;
  const int b0  = blockIdx.x * 4;
  const int row = t >> 7;
  const int ff  = t & 127;

  float wh0[16], wh1[16], wi0[16], wi1[16];
  {
    const float* p0 = Wh + f0*EMB + e0;
    const float* p1 = Wh + (f0+1)*EMB + e0;
    const float* q0 = Win + f0*EMB + e0;
    const float* q1 = Win + (f0+1)*EMB + e0;
#pragma unroll
    for (int q = 0; q < 4; ++q) {
      float4 a = ((const float4*)p0)[q];
      wh0[4*q+0]=a.x; wh0[4*q+1]=a.y; wh0[4*q+2]=a.z; wh0[4*q+3]=a.w;
      float4 b = ((const float4*)p1)[q];
      wh1[4*q+0]=b.x; wh1[4*q+1]=b.y; wh1[4*q+2]=b.z; wh1[4*q+3]=b.w;
      float4 c = ((const float4*)q0)[q];
      wi0[4*q+0]=c.x; wi0[4*q+1]=c.y; wi0[4*q+2]=c.z; wi0[4*q+3]=c.w;
      float4 d = ((const float4*)q1)[q];
      wi1[4*q+0]=d.x; wi1[4*q+1]=d.y; wi1[4*q+2]=d.z; wi1[4*q+3]=d.w;
    }
  }
  const float bc = bin[ff] + bh[ff];
  h_lds[row][ff] = 0.0f;
  for (int i = t; i < 4*SEQ; i += 512)
    x_lds[i / SEQ][i % SEQ] = xidx[(b0 + i/SEQ)*SEQ + (i % SEQ)];
  __syncthreads();
  emb_lds[0][row][ff] = emb[(long)x_lds[row][0]*EMB + ff];
  __syncthreads();

  int cur = 0;
  for (int s = 0; s < SEQ; ++s) {
    float nxt = 0.0f;
    if (s + 1 < SEQ) nxt = emb[(long)x_lds[row][s+1]*EMB + ff];
    float pa0[4], pa1[4];
#pragma unroll
    for (int rq = 0; rq < 4; ++rq) { pa0[rq] = 0.0f; pa1[rq] = 0.0f; }
#pragma unroll
    for (int rq = 0; rq < 4; ++rq) {
      const float4* hp  = (const float4*)&h_lds[rq][e0];
      const float4* epv = (const float4*)&emb_lds[cur][rq][e0];
#pragma unroll
      for (int q = 0; q < 4; ++q) {
        float4 hv = hp[q], ev = epv[q];
        pa0[rq] = fmaf(hv.x, wh0[4*q+0], pa0[rq]); pa0[rq] = fmaf(hv.y, wh0[4*q+1], pa0[rq]);
        pa0[rq] = fmaf(hv.z, wh0[4*q+2], pa0[rq]); pa0[rq] = fmaf(hv.w, wh0[4*q+3], pa0[rq]);
        pa1[rq] = fmaf(hv.x, wh1[4*q+0], pa1[rq]); pa1[rq] = fmaf(hv.y, wh1[4*q+1], pa1[rq]);
        pa1[rq] = fmaf(hv.z, wh1[4*q+2], pa1[rq]); pa1[rq] = fmaf(hv.w, wh1[4*q+3], pa1[rq]);
        pa0[rq] = fmaf(ev.x, wi0[4*q+0], pa0[rq]); pa0[rq] = fmaf(ev.y, wi0[4*q+1], pa0[rq]);
        pa0[rq] = fmaf(ev.z, wi0[4*q+2], pa0[rq]); pa0[rq] = fmaf(ev.w, wi0[4*q+3], pa0[rq]);
        pa1[rq] = fmaf(ev.x, wi1[4*q+0], pa1[rq]); pa1[rq] = fmaf(ev.y, wi1[4*q+1], pa1[rq]);
        pa1[rq] = fmaf(ev.z, wi1[4*q+2], pa1[rq]); pa1[rq] = fmaf(ev.w, wi1[4*q+3], pa1[rq]);
      }
    }
#pragma unroll
    for (int rq = 0; rq < 4; ++rq) {
      part[eg][rq][f0]   = pa0[rq];
      part[eg][rq][f0+1] = pa1[rq];
    }
    __syncthreads();
    float acc = bc;
#pragma unroll
    for (int g = 0; g < 8; ++g) acc += part[g][row][ff];
    float hn = tanhf(acc);
    if (s + 1 < SEQ) emb_lds[cur ^ 1][row][ff] = nxt;
    h_lds[row][ff] = hn;
    __syncthreads();
    cur ^= 1;
  }
  float hv = h_lds[row][ff];
  float sq = hv * hv;
#pragma unroll
  for (int off = 32; off > 0; off >>= 1) sq += __shfl_xor(sq, off, 64);
  if ((t & 63) == 0) red[t >> 6] = sq;
  __syncthreads();
  float nrm = sqrtf(red[row*2] + red[row*2 + 1]);
  out[(b0 + row)*EMB + ff] = hv / fmaxf(nrm, 1e-12f);
}

// ---------------------------------------------------------------------------
extern "C" void kernel_launch(void* const* d_in, const int* in_sizes, int n_in,
                              void* d_out, int out_size, void* d_ws, size_t ws_size,
                              hipStream_t stream) {
  const int*   x    = (const int*)  d_in[0];
  const float* emb  = (const float*)d_in[1];
  const float* Win  = (const float*)d_in[2];
  const float* bin  = (const float*)d_in[3];
  const float* Wh   = (const float*)d_in[4];
  const float* bh   = (const float*)d_in[5];
  float* out = (float*)d_out;

  const size_t need = (size_t)VOCAB * EMB * sizeof(unsigned short);  // 25.6 MB
  if (ws_size >= need) {
    unsigned short* embb = (unsigned short*)d_ws;
    cvt_emb<<<(VOCAB*EMB)/(256*8), 256, 0, stream>>>(emb, embb);
    rnn3<<<BATCH/16, 256, 0, stream>>>(x, embb, Win, bin, Wh, bh, out);
  } else {
    rnn_fused<<<BATCH/4, 512, 0, stream>>>(x, emb, Win, bin, Wh, bh, out);
  }
}

// Round 4
// 178.834 us; speedup vs baseline: 1.4919x; 1.4385x over previous
//
#include <hip/hip_runtime.h>

#define BATCH 1024
#define SEQ   200
#define EMB   128
#define VOCAB 100000

typedef __attribute__((ext_vector_type(8))) short short8;
typedef __attribute__((ext_vector_type(4))) float f32x4;

__device__ __forceinline__ unsigned short f2bf(float x) {
  unsigned u = __float_as_uint(x);
  u += 0x7fffu + ((u >> 16) & 1u);
  return (unsigned short)(u >> 16);
}
__device__ __forceinline__ float bf2f(unsigned short b) {
  return __uint_as_float(((unsigned)b) << 16);
}

__device__ __forceinline__ void async_ld16(const void* g, void* l) {
  __builtin_amdgcn_global_load_lds(
      (__attribute__((address_space(1))) unsigned int*)(void*)g,
      (__attribute__((address_space(3))) unsigned int*)l, 16, 0, 0);
}

// ---------------------------------------------------------------------------
// One-time: emb table fp32 -> bf16.
// ---------------------------------------------------------------------------
__global__ __launch_bounds__(256) void cvt_emb(const float* __restrict__ src,
                                               unsigned short* __restrict__ dst) {
  size_t i = ((size_t)blockIdx.x * 256 + threadIdx.x) * 8;
  float4 a = *(const float4*)(src + i);
  float4 b = *(const float4*)(src + i + 4);
  short8 o;
  o[0]=(short)f2bf(a.x); o[1]=(short)f2bf(a.y); o[2]=(short)f2bf(a.z); o[3]=(short)f2bf(a.w);
  o[4]=(short)f2bf(b.x); o[5]=(short)f2bf(b.y); o[6]=(short)f2bf(b.z); o[7]=(short)f2bf(b.w);
  *(short8*)(dst + i) = o;
}

// ---------------------------------------------------------------------------
// rnn4: 256 blocks (1/CU) x 512 thr (8 waves, 2/SIMD). Block owns 4 batch rows.
// Wave w owns f-tile [w*16, w*16+16). Per step, per wave:
//   16 MFMA (4 indep 4-chains: Win·emb + hi/lo-split Wh·h), 12 broadcast
//   ds_reads, 8 transcendentals, 2 b64 h-writes, 1 raw barrier.
// Only wave 0 runs the 8-slot emb DMA ring (1KB slots) + counted vmcnt(6).
// LDS tiles [4 r][128 e] bf16; chunk swizzle c ^= r<<2 (2-way max = free).
// MFMA cols 4..15 are duplicates of rows 0..3 (latency-bound; waste is free).
// ---------------------------------------------------------------------------
__global__ __launch_bounds__(512, 2) void rnn4(
    const int* __restrict__ xidx, const unsigned short* __restrict__ embb,
    const float* __restrict__ Win, const float* __restrict__ bin,
    const float* __restrict__ Wh,  const float* __restrict__ bh,
    float* __restrict__ out)
{
  __shared__ unsigned short ring[8][4][EMB];      // 8KB, swizzled chunks
  __shared__ unsigned short hbuf[2][2][4][EMB];   // 4KB: [buf][hi|lo][r][f]
  __shared__ int   xl[4][SEQ];                    // 3.2KB
  __shared__ float red[4][8];

  const int tid = threadIdx.x;
  const int w   = tid >> 6;          // 0..7
  const int l   = tid & 63;
  const int l15 = l & 15;
  const int lhi = l >> 4;            // 0..3
  const int r   = l15 & 3;           // owning batch row (l15>=4 duplicates)
  const int r0  = blockIdx.x * 4;

  // A-fragments: A[row=l15][k=kc*32+lhi*8+j] = W[w*16+l15][e]
  short8 wi[4], whh[4], whl[4];
  float bias[4];
  {
    const int frow = w*16 + l15;
    const float* pw = Win + frow*EMB;
    const float* ph = Wh  + frow*EMB;
#pragma unroll
    for (int kc = 0; kc < 4; ++kc) {
      float4 a = ((const float4*)(pw + kc*32 + lhi*8))[0];
      float4 b = ((const float4*)(pw + kc*32 + lhi*8))[1];
      float vw[8] = {a.x,a.y,a.z,a.w,b.x,b.y,b.z,b.w};
      float4 c = ((const float4*)(ph + kc*32 + lhi*8))[0];
      float4 d = ((const float4*)(ph + kc*32 + lhi*8))[1];
      float vh[8] = {c.x,c.y,c.z,c.w,d.x,d.y,d.z,d.w};
      short8 fw, fh, fl;
#pragma unroll
      for (int j = 0; j < 8; ++j) {
        fw[j] = (short)f2bf(vw[j]);
        unsigned short hq = f2bf(vh[j]);
        fh[j] = (short)hq;
        fl[j] = (short)f2bf(vh[j] - bf2f(hq));
      }
      wi[kc] = fw; whh[kc] = fh; whl[kc] = fl;
    }
    const int fo = w*16 + lhi*4;
#pragma unroll
    for (int j = 0; j < 4; ++j) bias[j] = bin[fo + j] + bh[fo + j];
  }

  // stage x indices; zero h buffer 0 (hi+lo = 1024 ushort = 512 uint)
  for (int i = tid; i < 4*SEQ; i += 512)
    xl[i / SEQ][i % SEQ] = xidx[(r0 + i/SEQ)*SEQ + (i % SEQ)];
  if (tid < 512) ((unsigned int*)&hbuf[0][0][0][0])[tid] = 0u;
  __syncthreads();   // full drain once (weights/x loads retired; vmcnt==0)

  // DMA geometry (wave 0): lane i -> ring[slot] linear dest (= [i>>4][ (i&15)*16 ]),
  // source chunk pre-swizzled: c_src = (i&15) ^ (r<<2)  (involution with read side)
  const char* ebase = (const char*)embb;
  const size_t srcoff = (size_t)(((l & 15) ^ ((l >> 4) << 2)) * 16);
  int gx = 0;
  if (w == 0) {
    const int rr = l >> 4;
#pragma unroll
    for (int p = 0; p < 7; ++p)
      async_ld16(ebase + (size_t)xl[rr][p]*256 + srcoff, &ring[p][0][0]);
    gx = xl[rr][7];
    asm volatile("s_waitcnt vmcnt(6) lgkmcnt(0)\n\ts_barrier" ::: "memory");
  } else {
    asm volatile("s_waitcnt lgkmcnt(0)\n\ts_barrier" ::: "memory");
  }

  float hfin[4];
  for (int s = 0; s < SEQ; ++s) {
    if (w == 0) {
      async_ld16(ebase + (size_t)gx*256 + srcoff, &ring[(s + 7) & 7][0][0]);
      int nt = s + 8; if (nt >= SEQ) nt = SEQ - 1;
      gx = xl[l >> 4][nt];
    }

    // B-fragments: B[k=kc*32+lhi*8+j][col] with col->r ; broadcast for l15>=4
    const char* eb = (const char*)&ring[s & 7][0][0];
    const char* th = (const char*)&hbuf[s & 1][0][0][0];
    const char* tl = (const char*)&hbuf[s & 1][1][0][0];
    short8 ef[4], hh[4], hl[4];
#pragma unroll
    for (int kc = 0; kc < 4; ++kc) {
      const int off = r*256 + (((kc*4 + lhi) ^ (r << 2)) * 16);
      ef[kc] = *(const short8*)(eb + off);
      hh[kc] = *(const short8*)(th + off);
      hl[kc] = *(const short8*)(tl + off);
    }

    f32x4 ae = (f32x4)(0.0f), a0 = (f32x4)(0.0f),
          a1 = (f32x4)(0.0f), a2 = (f32x4)(0.0f);
#pragma unroll
    for (int kc = 0; kc < 4; ++kc) {
      ae = __builtin_amdgcn_mfma_f32_16x16x32_bf16(wi[kc],  ef[kc], ae, 0, 0, 0);
      a0 = __builtin_amdgcn_mfma_f32_16x16x32_bf16(whh[kc], hh[kc], a0, 0, 0, 0);
      a1 = __builtin_amdgcn_mfma_f32_16x16x32_bf16(whh[kc], hl[kc], a1, 0, 0, 0);
      a2 = __builtin_amdgcn_mfma_f32_16x16x32_bf16(whl[kc], hh[kc], a2, 0, 0, 0);
    }

    // D: col=l15 -> r, row=lhi*4+j -> f = w*16+lhi*4+j. tanh, pack hi/lo.
    unsigned long long hi4 = 0ull, lo4 = 0ull;
#pragma unroll
    for (int j = 0; j < 4; ++j) {
      float v  = ae[j] + a0[j] + a1[j] + a2[j] + bias[j];
      float e2 = __expf(2.0f * v);
      float hn = 1.0f - __fdividef(2.0f, e2 + 1.0f);
      hfin[j] = hn;
      unsigned short hq = f2bf(hn);
      unsigned short lq = f2bf(hn - bf2f(hq));
      hi4 |= (unsigned long long)hq << (16*j);
      lo4 |= (unsigned long long)lq << (16*j);
    }
    if (l15 < 4) {
      char* nh = (char*)&hbuf[(s & 1) ^ 1][0][0][0];
      char* nl = (char*)&hbuf[(s & 1) ^ 1][1][0][0];
      const int cf = w*2 + (lhi >> 1);
      const int off = r*256 + ((cf ^ (r << 2)) * 16) + (lhi & 1)*8;
      *(unsigned long long*)(nh + off) = hi4;
      *(unsigned long long*)(nl + off) = lo4;
    }

    if (w == 0)
      asm volatile("s_waitcnt vmcnt(6) lgkmcnt(0)\n\ts_barrier" ::: "memory");
    else
      asm volatile("s_waitcnt lgkmcnt(0)\n\ts_barrier" ::: "memory");
  }

  // L2 normalize. Lane's hfin (l15<4) = h[r][f=w*16+lhi*4+j].
  float pj = hfin[0]*hfin[0] + hfin[1]*hfin[1] + hfin[2]*hfin[2] + hfin[3]*hfin[3];
  pj += __shfl_xor(pj, 16, 64);
  pj += __shfl_xor(pj, 32, 64);          // lanes 0..3 hold wave-partial for row l
  if (l < 4) red[l][w] = pj;
  asm volatile("s_waitcnt lgkmcnt(0)\n\ts_barrier" ::: "memory");
  float tot = 0.0f;
#pragma unroll
  for (int g = 0; g < 8; ++g) tot += red[r][g];
  const float inv = 1.0f / fmaxf(sqrtf(tot), 1e-12f);
  if (l15 < 4) {
    float4 o;
    o.x = hfin[0]*inv; o.y = hfin[1]*inv; o.z = hfin[2]*inv; o.w = hfin[3]*inv;
    *(float4*)(out + (size_t)(r0 + r)*EMB + w*16 + lhi*4) = o;
  }
}

// ---------------------------------------------------------------------------
// Fallback (small ws): round-1 VALU recurrence (known-correct, no scratch).
// ---------------------------------------------------------------------------
__global__ __launch_bounds__(512) void rnn_fused(
    const int* __restrict__ xidx, const float* __restrict__ emb,
    const float* __restrict__ Win, const float* __restrict__ bin,
    const float* __restrict__ Wh,  const float* __restrict__ bh,
    float* __restrict__ out)
{
  __shared__ float h_lds[4][EMB];
  __shared__ float part[8][4][EMB];
  __shared__ float emb_lds[2][4][EMB];
  __shared__ int   x_lds[4][SEQ];
  __shared__ float red[8];

  const int t   = threadIdx.x;
  const int f0  = (t & 63) * 2;
  const int eg  = t >> 6;
  const int e0  = eg * 16;
  const int b0  = blockIdx.x * 4;
  const int row = t >> 7;
  const int ff  = t & 127;

  float wh0[16], wh1[16], wi0[16], wi1[16];
  {
    const float* p0 = Wh + f0*EMB + e0;
    const float* p1 = Wh + (f0+1)*EMB + e0;
    const float* q0 = Win + f0*EMB + e0;
    const float* q1 = Win + (f0+1)*EMB + e0;
#pragma unroll
    for (int q = 0; q < 4; ++q) {
      float4 a = ((const float4*)p0)[q];
      wh0[4*q+0]=a.x; wh0[4*q+1]=a.y; wh0[4*q+2]=a.z; wh0[4*q+3]=a.w;
      float4 b = ((const float4*)p1)[q];
      wh1[4*q+0]=b.x; wh1[4*q+1]=b.y; wh1[4*q+2]=b.z; wh1[4*q+3]=b.w;
      float4 c = ((const float4*)q0)[q];
      wi0[4*q+0]=c.x; wi0[4*q+1]=c.y; wi0[4*q+2]=c.z; wi0[4*q+3]=c.w;
      float4 d = ((const float4*)q1)[q];
      wi1[4*q+0]=d.x; wi1[4*q+1]=d.y; wi1[4*q+2]=d.z; wi1[4*q+3]=d.w;
    }
  }
  const float bc = bin[ff] + bh[ff];
  h_lds[row][ff] = 0.0f;
  for (int i = t; i < 4*SEQ; i += 512)
    x_lds[i / SEQ][i % SEQ] = xidx[(b0 + i/SEQ)*SEQ + (i % SEQ)];
  __syncthreads();
  emb_lds[0][row][ff] = emb[(long)x_lds[row][0]*EMB + ff];
  __syncthreads();

  int cur = 0;
  for (int s = 0; s < SEQ; ++s) {
    float nxt = 0.0f;
    if (s + 1 < SEQ) nxt = emb[(long)x_lds[row][s+1]*EMB + ff];
    float pa0[4], pa1[4];
#pragma unroll
    for (int rq = 0; rq < 4; ++rq) { pa0[rq] = 0.0f; pa1[rq] = 0.0f; }
#pragma unroll
    for (int rq = 0; rq < 4; ++rq) {
      const float4* hp  = (const float4*)&h_lds[rq][e0];
      const float4* epv = (const float4*)&emb_lds[cur][rq][e0];
#pragma unroll
      for (int q = 0; q < 4; ++q) {
        float4 hv = hp[q], ev = epv[q];
        pa0[rq] = fmaf(hv.x, wh0[4*q+0], pa0[rq]); pa0[rq] = fmaf(hv.y, wh0[4*q+1], pa0[rq]);
        pa0[rq] = fmaf(hv.z, wh0[4*q+2], pa0[rq]); pa0[rq] = fmaf(hv.w, wh0[4*q+3], pa0[rq]);
        pa1[rq] = fmaf(hv.x, wh1[4*q+0], pa1[rq]); pa1[rq] = fmaf(hv.y, wh1[4*q+1], pa1[rq]);
        pa1[rq] = fmaf(hv.z, wh1[4*q+2], pa1[rq]); pa1[rq] = fmaf(hv.w, wh1[4*q+3], pa1[rq]);
        pa0[rq] = fmaf(ev.x, wi0[4*q+0], pa0[rq]); pa0[rq] = fmaf(ev.y, wi0[4*q+1], pa0[rq]);
        pa0[rq] = fmaf(ev.z, wi0[4*q+2], pa0[rq]); pa0[rq] = fmaf(ev.w, wi0[4*q+3], pa0[rq]);
        pa1[rq] = fmaf(ev.x, wi1[4*q+0], pa1[rq]); pa1[rq] = fmaf(ev.y, wi1[4*q+1], pa1[rq]);
        pa1[rq] = fmaf(ev.z, wi1[4*q+2], pa1[rq]); pa1[rq] = fmaf(ev.w, wi1[4*q+3], pa1[rq]);
      }
    }
#pragma unroll
    for (int rq = 0; rq < 4; ++rq) {
      part[eg][rq][f0]   = pa0[rq];
      part[eg][rq][f0+1] = pa1[rq];
    }
    __syncthreads();
    float acc = bc;
#pragma unroll
    for (int g = 0; g < 8; ++g) acc += part[g][row][ff];
    float hn = tanhf(acc);
    if (s + 1 < SEQ) emb_lds[cur ^ 1][row][ff] = nxt;
    h_lds[row][ff] = hn;
    __syncthreads();
    cur ^= 1;
  }
  float hv = h_lds[row][ff];
  float sq = hv * hv;
#pragma unroll
  for (int off = 32; off > 0; off >>= 1) sq += __shfl_xor(sq, off, 64);
  if ((t & 63) == 0) red[t >> 6] = sq;
  __syncthreads();
  float nrm = sqrtf(red[row*2] + red[row*2 + 1]);
  out[(b0 + row)*EMB + ff] = hv / fmaxf(nrm, 1e-12f);
}

// ---------------------------------------------------------------------------
extern "C" void kernel_launch(void* const* d_in, const int* in_sizes, int n_in,
                              void* d_out, int out_size, void* d_ws, size_t ws_size,
                              hipStream_t stream) {
  const int*   x    = (const int*)  d_in[0];
  const float* emb  = (const float*)d_in[1];
  const float* Win  = (const float*)d_in[2];
  const float* bin  = (const float*)d_in[3];
  const float* Wh   = (const float*)d_in[4];
  const float* bh   = (const float*)d_in[5];
  float* out = (float*)d_out;

  const size_t need = (size_t)VOCAB * EMB * sizeof(unsigned short);  // 25.6 MB
  if (ws_size >= need) {
    unsigned short* embb = (unsigned short*)d_ws;
    cvt_emb<<<(VOCAB*EMB)/(256*8), 256, 0, stream>>>(emb, embb);
    rnn4<<<BATCH/4, 512, 0, stream>>>(x, embb, Win, bin, Wh, bh, out);
  } else {
    rnn_fused<<<BATCH/4, 512, 0, stream>>>(x, emb, Win, bin, Wh, bh, out);
  }
}